// Round 1
// baseline (5471.179 us; speedup 1.0000x reference)
//
#include <hip/hip_runtime.h>

#define F 128

// out[n][f] = bias[f]
__global__ __launch_bounds__(256) void init_out_kernel(float* __restrict__ out,
                                                       const float* __restrict__ bias,
                                                       int n_nodes) {
    int idx = blockIdx.x * blockDim.x + threadIdx.x;
    int total = n_nodes * F;
    if (idx < total) out[idx] = bias[idx & (F - 1)];
}

// S = X @ W   (X: [n,128] fp32, W: [128,128] fp32)
// W staged in LDS (64 KB). Block = 256 threads = 8 row-slots x 32 feature-slots.
// Each thread computes 4 consecutive output features for its row.
__global__ __launch_bounds__(256) void gemm_xw_kernel(const float* __restrict__ X,
                                                      const float* __restrict__ W,
                                                      float* __restrict__ S,
                                                      int n_nodes) {
    __shared__ float Wl[F * F];  // 64 KB
    for (int i = threadIdx.x; i < F * F / 4; i += blockDim.x) {
        ((float4*)Wl)[i] = ((const float4*)W)[i];
    }
    __syncthreads();

    const int ROWS = 64;
    int rowBase = blockIdx.x * ROWS;
    int fbase = (threadIdx.x & 31) * 4;  // feature base (0..124)
    int rsub = threadIdx.x >> 5;         // 0..7

    for (int r = rsub; r < ROWS; r += 8) {
        int row = rowBase + r;
        if (row >= n_nodes) break;
        const float* xr = X + (size_t)row * F;
        float ax = 0.f, ay = 0.f, az = 0.f, aw = 0.f;
#pragma unroll 8
        for (int k = 0; k < F; ++k) {
            float xv = xr[k];  // broadcast across the 32 lanes of this row
            float4 wv = *(const float4*)&Wl[k * F + fbase];
            ax += xv * wv.x;
            ay += xv * wv.y;
            az += xv * wv.z;
            aw += xv * wv.w;
        }
        float4 res = {ax, ay, az, aw};
        *(float4*)&S[(size_t)row * F + fbase] = res;
    }
}

// For each edge e: out[dst[e]][:] += ew[e] * S[src[e]][:]
// 32 threads per edge, 4 features per thread, hardware fp32 atomics.
__global__ __launch_bounds__(256) void scatter_edges_kernel(const float* __restrict__ S,
                                                            const int* __restrict__ esrc,
                                                            const int* __restrict__ edst,
                                                            const float* __restrict__ ew,
                                                            float* __restrict__ out,
                                                            int n_edges) {
    long long idx = (long long)blockIdx.x * blockDim.x + threadIdx.x;
    int e = (int)(idx >> 5);
    if (e >= n_edges) return;
    int fbase = ((int)idx & 31) * 4;

    int s = esrc[e];
    int d = edst[e];
    float w = ew[e];

    float4 v = *(const float4*)&S[(size_t)s * F + fbase];
    float* o = out + (size_t)d * F + fbase;

    __hip_atomic_fetch_add(&o[0], v.x * w, __ATOMIC_RELAXED, __HIP_MEMORY_SCOPE_AGENT);
    __hip_atomic_fetch_add(&o[1], v.y * w, __ATOMIC_RELAXED, __HIP_MEMORY_SCOPE_AGENT);
    __hip_atomic_fetch_add(&o[2], v.z * w, __ATOMIC_RELAXED, __HIP_MEMORY_SCOPE_AGENT);
    __hip_atomic_fetch_add(&o[3], v.w * w, __ATOMIC_RELAXED, __HIP_MEMORY_SCOPE_AGENT);
}

extern "C" void kernel_launch(void* const* d_in, const int* in_sizes, int n_in,
                              void* d_out, int out_size, void* d_ws, size_t ws_size,
                              hipStream_t stream) {
    const float* x    = (const float*)d_in[0];
    const float* w    = (const float*)d_in[1];
    const float* bias = (const float*)d_in[2];
    const int*   esrc = (const int*)d_in[3];
    const int*   edst = (const int*)d_in[4];
    const float* ew   = (const float*)d_in[5];
    float* out = (float*)d_out;

    int n_nodes = in_sizes[0] / F;
    int n_edges = in_sizes[3];

    float* S = (float*)d_ws;  // [n_nodes * F] fp32 = 51.2 MB scratch

    // out = bias (broadcast)
    {
        int total = n_nodes * F;
        init_out_kernel<<<(total + 255) / 256, 256, 0, stream>>>(out, bias, n_nodes);
    }

    // S = X @ W
    {
        int blocks = (n_nodes + 63) / 64;
        gemm_xw_kernel<<<blocks, 256, 0, stream>>>(x, w, S, n_nodes);
    }

    // scatter-add over edges (depends on both previous kernels; stream-ordered)
    {
        long long total = (long long)n_edges * 32;
        int blocks = (int)((total + 255) / 256);
        scatter_edges_kernel<<<blocks, 256, 0, stream>>>(S, esrc, edst, ew, out, n_edges);
    }
}

// Round 2
// 738.193 us; speedup vs baseline: 7.4116x; 7.4116x over previous
//
#include <hip/hip_runtime.h>

#define F 128
#define CH 1024          // scan chunk (elements per block)
#define MAXCHUNKS 256

// ---------------- GEMM: S = X @ W ----------------
__global__ __launch_bounds__(256) void gemm_xw_kernel(const float* __restrict__ X,
                                                      const float* __restrict__ W,
                                                      float* __restrict__ S,
                                                      int n_nodes) {
    __shared__ float Wl[F * F];  // 64 KB
    for (int i = threadIdx.x; i < F * F / 4; i += blockDim.x) {
        ((float4*)Wl)[i] = ((const float4*)W)[i];
    }
    __syncthreads();

    const int ROWS = 64;
    int rowBase = blockIdx.x * ROWS;
    int fbase = (threadIdx.x & 31) * 4;
    int rsub = threadIdx.x >> 5;

    for (int r = rsub; r < ROWS; r += 8) {
        int row = rowBase + r;
        if (row >= n_nodes) break;
        const float* xr = X + (size_t)row * F;
        float ax = 0.f, ay = 0.f, az = 0.f, aw = 0.f;
#pragma unroll 8
        for (int k = 0; k < F; ++k) {
            float xv = xr[k];
            float4 wv = *(const float4*)&Wl[k * F + fbase];
            ax += xv * wv.x; ay += xv * wv.y; az += xv * wv.z; aw += xv * wv.w;
        }
        float4 res = {ax, ay, az, aw};
        *(float4*)&S[(size_t)row * F + fbase] = res;
    }
}

// ---------------- CSR build ----------------
__global__ __launch_bounds__(256) void hist_kernel(const int* __restrict__ edst,
                                                   int* __restrict__ cnt, int n_edges) {
    for (int e = blockIdx.x * blockDim.x + threadIdx.x; e < n_edges;
         e += gridDim.x * blockDim.x) {
        __hip_atomic_fetch_add(&cnt[edst[e]], 1, __ATOMIC_RELAXED, __HIP_MEMORY_SCOPE_AGENT);
    }
}

// per-chunk totals
__global__ __launch_bounds__(256) void scan_reduce_kernel(const int* __restrict__ cnt,
                                                          int* __restrict__ chunk_sums, int n) {
    __shared__ int tmp[256];
    int b = blockIdx.x, t = threadIdx.x;
    int base = b * CH + t * (CH / 256);
    int s = 0;
#pragma unroll
    for (int i = 0; i < CH / 256; ++i) {
        int idx = base + i;
        s += (idx < n) ? cnt[idx] : 0;
    }
    tmp[t] = s;
    __syncthreads();
    for (int off = 128; off > 0; off >>= 1) {
        if (t < off) tmp[t] += tmp[t + off];
        __syncthreads();
    }
    if (t == 0) chunk_sums[b] = tmp[0];
}

// single-block exclusive scan of chunk sums (nchunks <= 256)
__global__ __launch_bounds__(256) void scan_top_kernel(int* __restrict__ chunk_sums, int nchunks) {
    __shared__ int tmp[256];
    int t = threadIdx.x;
    int v = (t < nchunks) ? chunk_sums[t] : 0;
    tmp[t] = v;
    __syncthreads();
    for (int off = 1; off < 256; off <<= 1) {
        int x = (t >= off) ? tmp[t - off] : 0;
        __syncthreads();
        tmp[t] += x;
        __syncthreads();
    }
    if (t < nchunks) chunk_sums[t] = tmp[t] - v;  // exclusive
}

// per-chunk exclusive scan + chunk offset -> row_start, cursor
__global__ __launch_bounds__(256) void scan_apply_kernel(const int* __restrict__ cnt,
                                                         const int* __restrict__ chunk_sums,
                                                         int* __restrict__ row_start,
                                                         int* __restrict__ cursor, int n) {
    __shared__ int tmp[256];
    int b = blockIdx.x, t = threadIdx.x;
    const int EPT = CH / 256;  // 4
    int base = b * CH + t * EPT;
    int v[EPT];
    int s = 0;
#pragma unroll
    for (int i = 0; i < EPT; ++i) {
        int idx = base + i;
        v[i] = (idx < n) ? cnt[idx] : 0;
        s += v[i];
    }
    tmp[t] = s;
    __syncthreads();
    for (int off = 1; off < 256; off <<= 1) {
        int x = (t >= off) ? tmp[t - off] : 0;
        __syncthreads();
        tmp[t] += x;
        __syncthreads();
    }
    int run = chunk_sums[b] + tmp[t] - s;  // exclusive prefix for this thread
#pragma unroll
    for (int i = 0; i < EPT; ++i) {
        int idx = base + i;
        if (idx < n) {
            row_start[idx] = run;
            cursor[idx] = run;
            run += v[i];
        }
    }
}

// scatter edges into CSR slots: csr[pos] = {src, bits(w)}
__global__ __launch_bounds__(256) void fill_kernel(const int* __restrict__ esrc,
                                                   const int* __restrict__ edst,
                                                   const float* __restrict__ ew,
                                                   int* __restrict__ cursor,
                                                   int2* __restrict__ csr, int n_edges) {
    for (int e = blockIdx.x * blockDim.x + threadIdx.x; e < n_edges;
         e += gridDim.x * blockDim.x) {
        int d = edst[e];
        int pos = __hip_atomic_fetch_add(&cursor[d], 1, __ATOMIC_RELAXED, __HIP_MEMORY_SCOPE_AGENT);
        int2 p;
        p.x = esrc[e];
        p.y = __float_as_int(ew[e]);
        csr[pos] = p;
    }
}

// one wave per dst node: out[d] = bias + sum_e w_e * S[src_e]
__global__ __launch_bounds__(256) void gather_kernel(const float* __restrict__ S,
                                                     const int2* __restrict__ csr,
                                                     const int* __restrict__ row_start,
                                                     const int* __restrict__ cnt,
                                                     const float* __restrict__ bias,
                                                     float* __restrict__ out, int n_nodes) {
    int node = blockIdx.x * 4 + (threadIdx.x >> 6);
    if (node >= n_nodes) return;
    int lane = threadIdx.x & 63;

    float2 acc = *(const float2*)&bias[lane * 2];
    int beg = row_start[node];
    int num = cnt[node];

    int i = 0;
    for (; i + 4 <= num; i += 4) {
        int2 p0 = csr[beg + i + 0];
        int2 p1 = csr[beg + i + 1];
        int2 p2 = csr[beg + i + 2];
        int2 p3 = csr[beg + i + 3];
        float2 v0 = *(const float2*)&S[(size_t)p0.x * F + lane * 2];
        float2 v1 = *(const float2*)&S[(size_t)p1.x * F + lane * 2];
        float2 v2 = *(const float2*)&S[(size_t)p2.x * F + lane * 2];
        float2 v3 = *(const float2*)&S[(size_t)p3.x * F + lane * 2];
        float w0 = __int_as_float(p0.y), w1 = __int_as_float(p1.y);
        float w2 = __int_as_float(p2.y), w3 = __int_as_float(p3.y);
        acc.x += w0 * v0.x; acc.y += w0 * v0.y;
        acc.x += w1 * v1.x; acc.y += w1 * v1.y;
        acc.x += w2 * v2.x; acc.y += w2 * v2.y;
        acc.x += w3 * v3.x; acc.y += w3 * v3.y;
    }
    for (; i < num; ++i) {
        int2 p = csr[beg + i];
        float2 v = *(const float2*)&S[(size_t)p.x * F + lane * 2];
        float w = __int_as_float(p.y);
        acc.x += w * v.x; acc.y += w * v.y;
    }
    *(float2*)&out[(size_t)node * F + lane * 2] = acc;
}

// ---------------- fallback (atomic) path ----------------
__global__ __launch_bounds__(256) void init_out_kernel(float* __restrict__ out,
                                                       const float* __restrict__ bias,
                                                       int n_nodes) {
    int idx = blockIdx.x * blockDim.x + threadIdx.x;
    int total = n_nodes * F;
    if (idx < total) out[idx] = bias[idx & (F - 1)];
}

__global__ __launch_bounds__(256) void scatter_edges_kernel(const float* __restrict__ S,
                                                            const int* __restrict__ esrc,
                                                            const int* __restrict__ edst,
                                                            const float* __restrict__ ew,
                                                            float* __restrict__ out,
                                                            int n_edges) {
    long long idx = (long long)blockIdx.x * blockDim.x + threadIdx.x;
    int e = (int)(idx >> 5);
    if (e >= n_edges) return;
    int fbase = ((int)idx & 31) * 4;
    int s = esrc[e];
    int d = edst[e];
    float w = ew[e];
    float4 v = *(const float4*)&S[(size_t)s * F + fbase];
    float* o = out + (size_t)d * F + fbase;
    __hip_atomic_fetch_add(&o[0], v.x * w, __ATOMIC_RELAXED, __HIP_MEMORY_SCOPE_AGENT);
    __hip_atomic_fetch_add(&o[1], v.y * w, __ATOMIC_RELAXED, __HIP_MEMORY_SCOPE_AGENT);
    __hip_atomic_fetch_add(&o[2], v.z * w, __ATOMIC_RELAXED, __HIP_MEMORY_SCOPE_AGENT);
    __hip_atomic_fetch_add(&o[3], v.w * w, __ATOMIC_RELAXED, __HIP_MEMORY_SCOPE_AGENT);
}

extern "C" void kernel_launch(void* const* d_in, const int* in_sizes, int n_in,
                              void* d_out, int out_size, void* d_ws, size_t ws_size,
                              hipStream_t stream) {
    const float* x    = (const float*)d_in[0];
    const float* w    = (const float*)d_in[1];
    const float* bias = (const float*)d_in[2];
    const int*   esrc = (const int*)d_in[3];
    const int*   edst = (const int*)d_in[4];
    const float* ew   = (const float*)d_in[5];
    float* out = (float*)d_out;

    int n_nodes = in_sizes[0] / F;
    int n_edges = in_sizes[3];
    int nchunks = (n_nodes + CH - 1) / CH;

    // workspace carve (256B aligned)
    size_t off = 0;
    auto carve = [&](size_t bytes) -> void* {
        void* p = (char*)d_ws + off;
        off += (bytes + 255) & ~(size_t)255;
        return p;
    };
    float* S        = (float*)carve((size_t)n_nodes * F * sizeof(float));
    int*   cnt      = (int*)carve((size_t)n_nodes * sizeof(int));
    int*   rowst    = (int*)carve((size_t)n_nodes * sizeof(int));
    int*   cursor   = (int*)carve((size_t)n_nodes * sizeof(int));
    int*   chunks   = (int*)carve((size_t)MAXCHUNKS * sizeof(int));
    int2*  csr      = (int2*)carve((size_t)n_edges * sizeof(int2));
    bool csr_ok = (off <= ws_size) && (nchunks <= MAXCHUNKS);

    // S = X @ W
    gemm_xw_kernel<<<(n_nodes + 63) / 64, 256, 0, stream>>>(x, w, S, n_nodes);

    if (csr_ok) {
        hipMemsetAsync(cnt, 0, (size_t)n_nodes * sizeof(int), stream);
        hist_kernel<<<1024, 256, 0, stream>>>(edst, cnt, n_edges);
        scan_reduce_kernel<<<nchunks, 256, 0, stream>>>(cnt, chunks, n_nodes);
        scan_top_kernel<<<1, 256, 0, stream>>>(chunks, nchunks);
        scan_apply_kernel<<<nchunks, 256, 0, stream>>>(cnt, chunks, rowst, cursor, n_nodes);
        fill_kernel<<<2048, 256, 0, stream>>>(esrc, edst, ew, cursor, csr, n_edges);
        gather_kernel<<<(n_nodes + 3) / 4, 256, 0, stream>>>(S, csr, rowst, cnt, bias, out,
                                                             n_nodes);
    } else {
        // fallback: atomic scatter (needs only S)
        int total = n_nodes * F;
        init_out_kernel<<<(total + 255) / 256, 256, 0, stream>>>(out, bias, n_nodes);
        long long t2 = (long long)n_edges * 32;
        scatter_edges_kernel<<<(int)((t2 + 255) / 256), 256, 0, stream>>>(S, esrc, edst, ew, out,
                                                                          n_edges);
    }
}